// Round 2
// 1255.980 us; speedup vs baseline: 1.0932x; 1.0932x over previous
//
#include <hip/hip_runtime.h>
#include <cstdint>
#include <cstddef>

#define T_LEN 8192
#define DIMC  256
#define NBUCK 128
#define BHEAD 32
#define MROWS 32768

typedef __attribute__((ext_vector_type(8))) short bf16x8;
typedef __attribute__((ext_vector_type(4))) float f32x4;

__device__ __forceinline__ ushort f2bf(float x) {
  union { float f; unsigned u; } v; v.f = x;
  unsigned r = v.u + 0x7fffu + ((v.u >> 16) & 1u);
  return (ushort)(r >> 16);
}
__device__ __forceinline__ float bf2f(ushort u) {
  union { unsigned u; float f; } v; v.u = ((unsigned)u) << 16; return v.f;
}

__device__ __forceinline__ void gld16(const void* g, void* l) {
  __builtin_amdgcn_global_load_lds((const __attribute__((address_space(1))) void*)g,
                                   (__attribute__((address_space(3))) void*)l, 16, 0, 0);
}

// gelu with A&S 7.1.26 erf (|err| <= 1.5e-7)
__device__ __forceinline__ float fast_gelu(float v) {
  float x = v * 0.70710678118654752f;
  float ax = fabsf(x);
  float t = 1.0f / fmaf(0.3275911f, ax, 1.0f);
  float poly = t * fmaf(t, fmaf(t, fmaf(t, fmaf(t, 1.061405429f, -1.453152027f),
                                        1.421413741f), -0.284496736f), 0.254829592f);
  float e = __expf(-ax * ax);
  float er = 1.0f - poly * e;
  er = (x < 0.f) ? -er : er;
  return 0.5f * v * (1.0f + er);
}

// ---------------------------------------------------------------------------
// y[b,t,d] = x[b,d,t] + pe0[t/64,d] + pe1[t%64,d]
// ---------------------------------------------------------------------------
__global__ __launch_bounds__(256)
void add_pos_k(const float* __restrict__ x, const float* __restrict__ pe0,
               const float* __restrict__ pe1, float* __restrict__ y) {
  __shared__ float tile[32][33];
  int b  = blockIdx.z;
  int t0 = blockIdx.x * 32;
  int d0 = blockIdx.y * 32;
  int tj = threadIdx.x;
  int di = threadIdx.y;
#pragma unroll
  for (int k = 0; k < 4; k++) {
    int d = d0 + di + k * 8;
    tile[di + k * 8][tj] = x[((size_t)b * DIMC + d) * T_LEN + t0 + tj];
  }
  __syncthreads();
#pragma unroll
  for (int k = 0; k < 4; k++) {
    int t = t0 + di + k * 8;
    int d = d0 + tj;
    y[((size_t)b * T_LEN + t) * DIMC + d] =
        tile[tj][di + k * 8] + pe0[(size_t)(t >> 6) * DIMC + d] + pe1[(size_t)(t & 63) * DIMC + d];
  }
}

// ---------------------------------------------------------------------------
// Standalone LayerNorm (layer-0 LN1 only). Writes bf16.
// ---------------------------------------------------------------------------
__global__ __launch_bounds__(256)
void layernorm_k(const float* __restrict__ x, const float* __restrict__ g,
                 const float* __restrict__ b, ushort* __restrict__ o) {
  int row  = blockIdx.x * 4 + (threadIdx.x >> 6);
  int lane = threadIdx.x & 63;
  const float4* xr = (const float4*)(x + (size_t)row * DIMC);
  float4 v = xr[lane];
  float s  = v.x + v.y + v.z + v.w;
  float s2 = v.x * v.x + v.y * v.y + v.z * v.z + v.w * v.w;
#pragma unroll
  for (int off = 32; off; off >>= 1) {
    s  += __shfl_xor(s, off);
    s2 += __shfl_xor(s2, off);
  }
  float mean = s * (1.0f / 256.0f);
  float var  = s2 * (1.0f / 256.0f) - mean * mean;
  float r    = rsqrtf(var + 1e-5f);
  float4 gv = ((const float4*)g)[lane];
  float4 bv = ((const float4*)b)[lane];
  ushort4 o4;
  o4.x = f2bf((v.x - mean) * r * gv.x + bv.x);
  o4.y = f2bf((v.y - mean) * r * gv.y + bv.y);
  o4.z = f2bf((v.z - mean) * r * gv.z + bv.z);
  o4.w = f2bf((v.w - mean) * r * gv.w + bv.w);
  ((ushort4*)(o + (size_t)row * DIMC))[lane] = o4;
}

// ---------------------------------------------------------------------------
// weight convert: Wt[l][n][k] = bf16(W[l][k][n])
// ---------------------------------------------------------------------------
__global__ __launch_bounds__(256)
void wt_bf16_k(const float* __restrict__ W, ushort* __restrict__ Wt,
               int K, int N, size_t outStride) {
  __shared__ float t[32][33];
  int l = blockIdx.z;
  const float* Wl = W + (size_t)l * K * N;
  ushort* Wtl = Wt + (size_t)l * outStride;
  int n0 = blockIdx.x * 32, k0 = blockIdx.y * 32;
  int tx = threadIdx.x, ty = threadIdx.y;
#pragma unroll
  for (int p = 0; p < 4; p++)
    t[ty + p * 8][tx] = Wl[(size_t)(k0 + ty + p * 8) * N + n0 + tx];
  __syncthreads();
#pragma unroll
  for (int p = 0; p < 4; p++)
    Wtl[(size_t)(n0 + ty + p * 8) * K + k0 + tx] = f2bf(t[tx][ty + p * 8]);
}

// ---------------------------------------------------------------------------
// bf16 MFMA GEMM: epi(A(MxK,lda) @ Bt(NxK,ldb)^T [+bias]) -> bf16
// EPI 0: store. EPI 1: gelu(.+bias).
// Grid: (M/128, N/128) -- bm on x so all column tiles of one bm share an XCD.
// 128x128 tile, BK=32, 256 threads (2x2 waves), 4x4 MFMA per wave.
// Epilogue: per-wave LDS transpose -> bf16x8 coalesced stores.
// ---------------------------------------------------------------------------
template <int EPI>
__global__ __launch_bounds__(256)
void gemm_bf16(const ushort* __restrict__ A, const ushort* __restrict__ Bt,
               const float* __restrict__ bias, ushort* __restrict__ Cbf,
               int N, int K, int lda, int ldb) {
  __shared__ ushort As[128 * 32];
  __shared__ ushort Bs[128 * 32];
  __shared__ ushort eb[4][16][66];   // per-wave transpose buffer (pad 66)
  int tid = threadIdx.x;
  int w = tid >> 6, lane = tid & 63;
  int bm = blockIdx.x << 7, bn = blockIdx.y << 7;
  int wm = (w >> 1) << 6, wn = (w & 1) << 6;
  int l15 = lane & 15, quad = lane >> 4;

  int off0 = (w << 11) + (lane << 4);
  int off1 = off0 + 1024;
  int r0 = off0 >> 6, c0 = (off0 & 63) >> 1;
  int r1 = off1 >> 6, c1 = (off1 & 63) >> 1;
  const ushort* ga0 = A + (size_t)(bm + r0) * lda + c0;
  const ushort* ga1 = A + (size_t)(bm + r1) * lda + c1;
  const ushort* gb0 = Bt + (size_t)(bn + r0) * ldb + c0;
  const ushort* gb1 = Bt + (size_t)(bn + r1) * ldb + c1;
  ushort* lA0 = As + (w << 10);
  ushort* lA1 = lA0 + 512;
  ushort* lB0 = Bs + (w << 10);
  ushort* lB1 = lB0 + 512;

  f32x4 acc[4][4];
#pragma unroll
  for (int i = 0; i < 4; i++)
#pragma unroll
    for (int j = 0; j < 4; j++) {
      f32x4 z = {0.f, 0.f, 0.f, 0.f};
      acc[i][j] = z;
    }

  for (int k0 = 0; k0 < K; k0 += 32) {
    gld16(ga0 + k0, lA0);
    gld16(ga1 + k0, lA1);
    gld16(gb0 + k0, lB0);
    gld16(gb1 + k0, lB1);
    __syncthreads();
    bf16x8 aF[4], bF[4];
#pragma unroll
    for (int i = 0; i < 4; i++)
      aF[i] = *(const bf16x8*)(As + ((wm + (i << 4) + l15) << 5) + (quad << 3));
#pragma unroll
    for (int j = 0; j < 4; j++)
      bF[j] = *(const bf16x8*)(Bs + ((wn + (j << 4) + l15) << 5) + (quad << 3));
#pragma unroll
    for (int i = 0; i < 4; i++)
#pragma unroll
      for (int j = 0; j < 4; j++)
        acc[i][j] = __builtin_amdgcn_mfma_f32_16x16x32_bf16(aF[i], bF[j], acc[i][j], 0, 0, 0);
    __syncthreads();
  }

  float bvj[4];
  if (EPI == 1) {
#pragma unroll
    for (int j = 0; j < 4; j++) bvj[j] = bias[bn + wn + (j << 4) + l15];
  }
#pragma unroll
  for (int i = 0; i < 4; i++) {
    // 16 rows x 64 cols -> per-wave LDS (wave-local, no barrier needed)
#pragma unroll
    for (int j = 0; j < 4; j++) {
#pragma unroll
      for (int r = 0; r < 4; r++) {
        float v = acc[i][j][r];
        if (EPI == 1) v = fast_gelu(v + bvj[j]);
        eb[w][(quad << 2) + r][(j << 4) + l15] = f2bf(v);
      }
    }
#pragma unroll
    for (int h = 0; h < 2; h++) {
      int chunk = (h << 6) + lane;          // 0..127
      int row = chunk >> 3, c8 = (chunk & 7) << 3;
      bf16x8 vv = *(const bf16x8*)&eb[w][row][c8];
      *(bf16x8*)&Cbf[(size_t)(bm + wm + (i << 4) + row) * N + bn + wn + c8] = vv;
    }
  }
}

// ---------------------------------------------------------------------------
// GEMM + bias + residual + LayerNorm. 64-row blocks (grid M/64), 256 threads.
// Waves 2x2: wave tile = 32 rows x 128 cols (2 aF x 8 bF = 16 MFMA / K-step).
// Generic K (multiple of 32).
//   v = A@Bt^T + bias + y
//   FINAL=0: y = v ; obf = bf16(LN(v)) via LDS-transpose vector stores
//   FINAL=1: y = LN(v) (fp32 final)
// ---------------------------------------------------------------------------
template <int FINAL>
__global__ __launch_bounds__(256)
void oproj_ln_k(const ushort* __restrict__ A, const ushort* __restrict__ Bt,
                const float* __restrict__ bias, float* __restrict__ y,
                const float* __restrict__ g, const float* __restrict__ b,
                ushort* __restrict__ obf, int K, int lda) {
  // union: staging As(64x32) + Bs(256x32) = 10240 ushorts  |  eb 64x264 ushorts
  __shared__ ushort smem[64 * 264];
  __shared__ float red[2][64][2];
  __shared__ float stat[64][2];
  ushort* As = smem;            // 2048 ushorts
  ushort* Bs = smem + 2048;     // 8192 ushorts
  int tid = threadIdx.x;
  int wid = tid >> 6, lane = tid & 63;
  int l15 = lane & 15, quad = lane >> 4;
  int bm = blockIdx.x << 6;
  int wm = (wid >> 1) << 5;   // 0 / 32
  int wn = (wid & 1) << 7;    // 0 / 128

  // A staging: 64x32 bf16 = 4KB = 256 threads x 16B (1 issue)
  const ushort* gaA = A + (size_t)(bm + (tid >> 2)) * lda + ((tid & 3) << 3);
  ushort* lA = As + (tid << 3);
  // B staging: 256x32 bf16 = 16KB = 4 issues
  const ushort* gaB[4];
  ushort* lB[4];
#pragma unroll
  for (int p = 0; p < 4; p++) {
    int u = (p << 8) + tid;
    gaB[p] = Bt + (size_t)(u >> 2) * K + ((u & 3) << 3);
    lB[p] = Bs + (u << 3);
  }

  f32x4 acc[2][8];
#pragma unroll
  for (int i = 0; i < 2; i++)
#pragma unroll
    for (int j = 0; j < 8; j++) {
      f32x4 z = {0.f, 0.f, 0.f, 0.f};
      acc[i][j] = z;
    }

  for (int k0 = 0; k0 < K; k0 += 32) {
    gld16(gaA + k0, lA);
#pragma unroll
    for (int p = 0; p < 4; p++) gld16(gaB[p] + k0, lB[p]);
    __syncthreads();
    bf16x8 aF[2];
#pragma unroll
    for (int i = 0; i < 2; i++)
      aF[i] = *(const bf16x8*)(As + ((wm + (i << 4) + l15) << 5) + (quad << 3));
#pragma unroll
    for (int j = 0; j < 8; j++) {
      bf16x8 bF = *(const bf16x8*)(Bs + ((wn + (j << 4) + l15) << 5) + (quad << 3));
#pragma unroll
      for (int i = 0; i < 2; i++)
        acc[i][j] = __builtin_amdgcn_mfma_f32_16x16x32_bf16(aF[i], bF, acc[i][j], 0, 0, 0);
    }
    __syncthreads();
  }

  // epilogue: bias + residual (+ y store), per-row stats
  float bc[8];
#pragma unroll
  for (int j = 0; j < 8; j++) bc[j] = bias[wn + (j << 4) + l15];
  float s1v[2][4], s2v[2][4];
#pragma unroll
  for (int i = 0; i < 2; i++)
#pragma unroll
    for (int r = 0; r < 4; r++) {
      int row = bm + wm + (i << 4) + (quad << 2) + r;
      float s1 = 0.f, s2 = 0.f;
#pragma unroll
      for (int j = 0; j < 8; j++) {
        size_t idx = (size_t)row * 256 + wn + (j << 4) + l15;
        float v = acc[i][j][r] + bc[j] + y[idx];
        acc[i][j][r] = v;
        if (!FINAL) y[idx] = v;
        s1 += v;
        s2 += v * v;
      }
      s1v[i][r] = s1;
      s2v[i][r] = s2;
    }
#pragma unroll
  for (int off = 1; off < 16; off <<= 1)
#pragma unroll
    for (int i = 0; i < 2; i++)
#pragma unroll
      for (int r = 0; r < 4; r++) {
        s1v[i][r] += __shfl_xor(s1v[i][r], off);
        s2v[i][r] += __shfl_xor(s2v[i][r], off);
      }
  if (l15 == 0) {
#pragma unroll
    for (int i = 0; i < 2; i++)
#pragma unroll
      for (int r = 0; r < 4; r++) {
        int lr = wm + (i << 4) + (quad << 2) + r;
        red[wid & 1][lr][0] = s1v[i][r];
        red[wid & 1][lr][1] = s2v[i][r];
      }
  }
  __syncthreads();
  if (tid < 64) {
    float s  = red[0][tid][0] + red[1][tid][0];
    float s2 = red[0][tid][1] + red[1][tid][1];
    float mean = s * (1.0f / 256.0f);
    float var  = s2 * (1.0f / 256.0f) - mean * mean;
    stat[tid][0] = mean;
    stat[tid][1] = rsqrtf(var + 1e-5f);
  }
  __syncthreads();

  if (FINAL) {
#pragma unroll
    for (int j = 0; j < 8; j++) {
      int col = wn + (j << 4) + l15;
      float gc = g[col], bc2 = b[col];
#pragma unroll
      for (int i = 0; i < 2; i++)
#pragma unroll
        for (int r = 0; r < 4; r++) {
          int lr = wm + (i << 4) + (quad << 2) + r;
          float o = (acc[i][j][r] - stat[lr][0]) * stat[lr][1] * gc + bc2;
          y[(size_t)(bm + lr) * 256 + col] = o;
        }
    }
  } else {
    // LN -> LDS transpose buffer (64 x 264 pad) -> bf16x8 coalesced stores
    ushort (*eb)[264] = (ushort(*)[264])smem;
#pragma unroll
    for (int j = 0; j < 8; j++) {
      int col = wn + (j << 4) + l15;
      float gc = g[col], bc2 = b[col];
#pragma unroll
      for (int i = 0; i < 2; i++)
#pragma unroll
        for (int r = 0; r < 4; r++) {
          int lr = wm + (i << 4) + (quad << 2) + r;
          float o = (acc[i][j][r] - stat[lr][0]) * stat[lr][1] * gc + bc2;
          eb[lr][col] = f2bf(o);
        }
    }
    __syncthreads();
#pragma unroll
    for (int h = 0; h < 8; h++) {
      int chunk = (h << 8) + tid;           // 0..2047
      int row = chunk >> 5, c8 = (chunk & 31) << 3;
      bf16x8 vv = *(const bf16x8*)&eb[row][c8];
      *(bf16x8*)&obf[(size_t)(bm + row) * 256 + c8] = vv;
    }
  }
}

// ---------------------------------------------------------------------------
// bucket summaries from packed qkv (ld 768): q at +0, k at +256
// ---------------------------------------------------------------------------
__global__ __launch_bounds__(64)
void summary_k(const ushort* __restrict__ qkv,
               float* __restrict__ sq, float* __restrict__ sk) {
  int blk = blockIdx.x;
  int bh = blk >> 7, ib = blk & 127;
  int b = bh >> 3, h = bh & 7;
  int lane = threadIdx.x;
  int d = lane & 31;
  bool isK = lane >= 32;
  size_t base = ((size_t)b * T_LEN + (size_t)ib * 64) * 768 + (isK ? 256 : 0) + h * 32 + d;
  float s = 0.f;
#pragma unroll 8
  for (int t = 0; t < 64; t++) s += bf2f(qkv[base + (size_t)t * 768]);
  s *= (1.0f / 64.0f);
  float* dst = isK ? sk : sq;
  dst[((size_t)bh * NBUCK + ib) * 32 + d] = s;
}

// ---------------------------------------------------------------------------
// routing
// ---------------------------------------------------------------------------
__global__ __launch_bounds__(64)
void route_k(const float* __restrict__ sq, const float* __restrict__ sk,
             int* __restrict__ ridx, float* __restrict__ rw) {
  int blk = blockIdx.x;
  int bh = blk >> 7, ib = blk & 127;
  int lane = threadIdx.x;
  const float* qrow = sq + ((size_t)bh * NBUCK + ib) * 32;
  const float* k0 = sk + ((size_t)bh * NBUCK + lane) * 32;
  const float* k1 = k0 + 64 * 32;
  float s0 = 0.f, s1 = 0.f;
#pragma unroll
  for (int d = 0; d < 32; d++) {
    float qd = qrow[d];
    s0 += qd * k0[d];
    s1 += qd * k1[d];
  }
  const float sc = 0.17677669529663687f * (4.0f / 3.0f);
  float L0 = s0 * sc, L1 = s1 * sc;
  float m = fmaxf(L0, L1);
#pragma unroll
  for (int off = 32; off; off >>= 1) m = fmaxf(m, __shfl_xor(m, off));
  float Z = expf(L0 - m) + expf(L1 - m);
#pragma unroll
  for (int off = 32; off; off >>= 1) Z += __shfl_xor(Z, off);
  float mv = (L1 > L0) ? L1 : L0;
  int mj = (L1 > L0) ? lane + 64 : lane;
#pragma unroll
  for (int off = 32; off; off >>= 1) {
    float ov = __shfl_xor(mv, off);
    int oj = __shfl_xor(mj, off);
    if (ov > mv || (ov == mv && oj < mj)) { mv = ov; mj = oj; }
  }
  if (lane == 0) {
    ridx[blk] = mj;
    rw[blk] = 1.0f / Z;
  }
}

// ---------------------------------------------------------------------------
// MFMA bucketed attention reading packed qkv (ld 768). Output bf16.
// ---------------------------------------------------------------------------
__global__ __launch_bounds__(256)
void attn_mfma_k(const ushort* __restrict__ qkv,
                 const int* __restrict__ ridx, const float* __restrict__ rw,
                 ushort* __restrict__ o) {
  __shared__ ushort Qs[64][40];
  __shared__ ushort Ks[128][40];
  __shared__ ushort Vt[32][136];
  __shared__ ushort Ps[4][16][136];
  int blk = blockIdx.x;
  int bh = blk >> 7, ib = blk & 127;
  int b = bh >> 3, h = bh & 7;
  int tid = threadIdx.x;
  int jr = ridx[blk];
  float w = rw[blk];
  {
    int r = tid >> 2, c = (tid & 3) << 3;
    const ushort* src = qkv + ((size_t)b * T_LEN + (size_t)ib * 64 + r) * 768 + h * 32 + c;
    *(bf16x8*)&Qs[r][c] = *(const bf16x8*)src;
  }
#pragma unroll
  for (int p = 0; p < 2; p++) {
    int idx = tid + (p << 8);
    int r = idx >> 2, c = (idx & 3) << 3;
    int srcb = (r < 64) ? jr : ib;
    int tt = r & 63;
    const ushort* src = qkv + ((size_t)b * T_LEN + (size_t)srcb * 64 + tt) * 768 + 256 + h * 32 + c;
    *(bf16x8*)&Ks[r][c] = *(const bf16x8*)src;
  }
  {
    int tok = tid >> 1, d0 = (tid & 1) << 4;
    int srcb = (tok < 64) ? jr : ib;
    int tt = tok & 63;
    const ushort* src = qkv + ((size_t)b * T_LEN + (size_t)srcb * 64 + tt) * 768 + 512 + h * 32 + d0;
    bf16x8 v0 = *(const bf16x8*)src;
    bf16x8 v1 = *(const bf16x8*)(src + 8);
#pragma unroll
    for (int j = 0; j < 8; j++) {
      Vt[d0 + j][tok] = (ushort)v0[j];
      Vt[d0 + 8 + j][tok] = (ushort)v1[j];
    }
  }
  __syncthreads();
  int wid = tid >> 6, lane = tid & 63, l15 = lane & 15, quad = lane >> 4;
  bf16x8 aQ = *(const bf16x8*)&Qs[(wid << 4) + l15][quad << 3];
  f32x4 sf[8];
#pragma unroll
  for (int jn = 0; jn < 8; jn++) {
    bf16x8 bK = *(const bf16x8*)&Ks[(jn << 4) + l15][quad << 3];
    f32x4 z = {0.f, 0.f, 0.f, 0.f};
    sf[jn] = __builtin_amdgcn_mfma_f32_16x16x32_bf16(aQ, bK, z, 0, 0, 0);
  }
  const float sc = 0.17677669529663687f;
#pragma unroll
  for (int jn = 0; jn < 8; jn++) {
    float mult = (jn < 4) ? w * sc : sc;
#pragma unroll
    for (int r = 0; r < 4; r++) sf[jn][r] *= mult;
  }
  float mx[4], sm[4], inv[4];
#pragma unroll
  for (int r = 0; r < 4; r++) {
    float m = sf[0][r];
#pragma unroll
    for (int jn = 1; jn < 8; jn++) m = fmaxf(m, sf[jn][r]);
    mx[r] = m;
  }
#pragma unroll
  for (int off = 1; off < 16; off <<= 1)
#pragma unroll
    for (int r = 0; r < 4; r++) mx[r] = fmaxf(mx[r], __shfl_xor(mx[r], off));
#pragma unroll
  for (int r = 0; r < 4; r++) sm[r] = 0.f;
#pragma unroll
  for (int jn = 0; jn < 8; jn++)
#pragma unroll
    for (int r = 0; r < 4; r++) {
      sf[jn][r] = expf(sf[jn][r] - mx[r]);
      sm[r] += sf[jn][r];
    }
#pragma unroll
  for (int off = 1; off < 16; off <<= 1)
#pragma unroll
    for (int r = 0; r < 4; r++) sm[r] += __shfl_xor(sm[r], off);
#pragma unroll
  for (int r = 0; r < 4; r++) inv[r] = 1.0f / sm[r];
#pragma unroll
  for (int jn = 0; jn < 8; jn++) {
    float ws2 = (jn < 4) ? w : 1.f;
#pragma unroll
    for (int r = 0; r < 4; r++)
      Ps[wid][(quad << 2) + r][(jn << 4) + l15] = f2bf(sf[jn][r] * inv[r] * ws2);
  }
  f32x4 of[2];
#pragma unroll
  for (int nd = 0; nd < 2; nd++) { f32x4 z = {0.f, 0.f, 0.f, 0.f}; of[nd] = z; }
#pragma unroll
  for (int kk = 0; kk < 4; kk++) {
    bf16x8 aP = *(const bf16x8*)&Ps[wid][l15][(kk << 5) + (quad << 3)];
#pragma unroll
    for (int nd = 0; nd < 2; nd++) {
      bf16x8 bV = *(const bf16x8*)&Vt[(nd << 4) + l15][(kk << 5) + (quad << 3)];
      of[nd] = __builtin_amdgcn_mfma_f32_16x16x32_bf16(aP, bV, of[nd], 0, 0, 0);
    }
  }
  ushort* obase = o + ((size_t)b * T_LEN + (size_t)ib * 64 + (wid << 4) + (quad << 2)) * 256 + h * 32 + l15;
#pragma unroll
  for (int nd = 0; nd < 2; nd++)
#pragma unroll
    for (int r = 0; r < 4; r++)
      obase[(size_t)r * 256 + (nd << 4)] = f2bf(of[nd][r]);
}

// ---------------------------------------------------------------------------
// out[b,d,t] = yln[b,t,d]
// ---------------------------------------------------------------------------
__global__ __launch_bounds__(256)
void transpose_out_k(const float* __restrict__ yln, float* __restrict__ out) {
  __shared__ float tile[32][33];
  int b  = blockIdx.z;
  int t0 = blockIdx.x * 32;
  int d0 = blockIdx.y * 32;
  int tx = threadIdx.x;
  int ty = threadIdx.y;
#pragma unroll
  for (int k = 0; k < 4; k++) {
    int t = t0 + ty + k * 8;
    tile[ty + k * 8][tx] = yln[((size_t)b * T_LEN + t) * DIMC + d0 + tx];
  }
  __syncthreads();
#pragma unroll
  for (int k = 0; k < 4; k++) {
    int d = d0 + ty + k * 8;
    out[((size_t)b * DIMC + d) * T_LEN + t0 + tx] = tile[tx][ty + k * 8];
  }
}

// ---------------------------------------------------------------------------
extern "C" void kernel_launch(void* const* d_in, const int* in_sizes, int n_in,
                              void* d_out, int out_size, void* d_ws, size_t ws_size,
                              hipStream_t stream) {
  const float* x     = (const float*)d_in[0];
  const float* pe0   = (const float*)d_in[1];
  const float* pe1   = (const float*)d_in[2];
  const float* ln1_g = (const float*)d_in[3];
  const float* ln1_b = (const float*)d_in[4];
  const float* Wq    = (const float*)d_in[5];
  const float* Wkv   = (const float*)d_in[6];
  const float* Wo    = (const float*)d_in[7];
  const float* bo    = (const float*)d_in[8];
  const float* ln2_g = (const float*)d_in[9];
  const float* ln2_b = (const float*)d_in[10];
  const float* W1    = (const float*)d_in[11];
  const float* b1    = (const float*)d_in[12];
  const float* W2    = (const float*)d_in[13];
  const float* b2    = (const float*)d_in[14];
  const float* gf    = (const float*)d_in[15];
  const float* bfp   = (const float*)d_in[16];
  float* out = (float*)d_out;

  const int M = MROWS;
  float*  y    = (float*)d_ws;                       // M*256 f32
  ushort* qkv  = (ushort*)(y + (size_t)M * 256);     // M*768 bf16
  ushort* bufA = qkv + (size_t)M * 768;              // attn out (bf16)
  ushort* bufB = bufA + (size_t)M * 256;             // LN out (bf16)
  ushort* wbf  = bufB + (size_t)M * 256;             // 6*786432 transposed weights
  float*  sqb  = (float*)(wbf + (size_t)6 * 786432);
  float*  skb  = sqb + 131072;
  float*  rwb  = skb + 131072;
  int*    rib  = (int*)(rwb + 4096);
  ushort* ffbf = qkv;   // FF intermediate (M*1024) overlays dead qkv+bufA

  dim3 tb(32, 8);
  wt_bf16_k<<<dim3(8, 8, 6),  tb, 0, stream>>>(Wq,  wbf + 0,      256, 256,  786432);
  wt_bf16_k<<<dim3(16, 8, 6), tb, 0, stream>>>(Wkv, wbf + 65536,  256, 512,  786432);
  wt_bf16_k<<<dim3(8, 8, 6),  tb, 0, stream>>>(Wo,  wbf + 196608, 256, 256,  786432);
  wt_bf16_k<<<dim3(32, 8, 6), tb, 0, stream>>>(W1,  wbf + 262144, 256, 1024, 786432);
  wt_bf16_k<<<dim3(8, 32, 6), tb, 0, stream>>>(W2,  wbf + 524288, 1024, 256, 786432);

  add_pos_k<<<dim3(T_LEN / 32, DIMC / 32, 4), tb, 0, stream>>>(x, pe0, pe1, y);
  layernorm_k<<<M / 4, 256, 0, stream>>>(y, ln1_g, ln1_b, bufB);   // layer-0 LN1

  for (int l = 0; l < 6; l++) {
    const ushort* wl    = wbf + (size_t)l * 786432;
    const ushort* wqkvT = wl;
    const ushort* woT   = wl + 196608;
    const ushort* w1T   = wl + 262144;
    const ushort* w2T   = wl + 524288;

    gemm_bf16<0><<<dim3(M / 128, 6), 256, 0, stream>>>(bufB, wqkvT, nullptr, qkv, 768, 256, 256, 256);
    summary_k<<<BHEAD * NBUCK, 64, 0, stream>>>(qkv, sqb, skb);
    route_k<<<BHEAD * NBUCK, 64, 0, stream>>>(sqb, skb, rib, rwb);
    attn_mfma_k<<<BHEAD * NBUCK, 256, 0, stream>>>(qkv, rib, rwb, bufA);
    // o-proj + bias + residual + LN2 -> bufB (K=256)
    oproj_ln_k<0><<<M / 64, 256, 0, stream>>>(bufA, woT, bo + l * 256, y,
                                              ln2_g + l * 256, ln2_b + l * 256,
                                              bufB, 256, 256);
    // FF1 + gelu -> ffbf (overlays dead qkv+bufA)
    gemm_bf16<1><<<dim3(M / 128, 8), 256, 0, stream>>>(bufB, w1T, b1 + l * 1024, ffbf, 1024, 256, 256, 256);
    // FF2 + bias + residual + LN (next LN1 / final LN), K=1024
    if (l < 5) {
      oproj_ln_k<0><<<M / 64, 256, 0, stream>>>(ffbf, w2T, b2 + l * 256, y,
                                                ln1_g + (l + 1) * 256, ln1_b + (l + 1) * 256,
                                                bufB, 1024, 1024);
    } else {
      oproj_ln_k<1><<<M / 64, 256, 0, stream>>>(ffbf, w2T, b2 + l * 256, y,
                                                gf, bfp, nullptr, 1024, 1024);
    }
  }

  transpose_out_k<<<dim3(T_LEN / 32, DIMC / 32, 4), tb, 0, stream>>>(y, out);

  (void)in_sizes; (void)n_in; (void)out_size; (void)ws_size;
}

// Round 3
// 1167.005 us; speedup vs baseline: 1.1766x; 1.0762x over previous
//
#include <hip/hip_runtime.h>
#include <cstdint>
#include <cstddef>

#define T_LEN 8192
#define DIMC  256
#define NBUCK 128
#define BHEAD 32
#define MROWS 32768

typedef __attribute__((ext_vector_type(8))) short bf16x8;
typedef __attribute__((ext_vector_type(4))) float f32x4;

__device__ __forceinline__ ushort f2bf(float x) {
  union { float f; unsigned u; } v; v.f = x;
  unsigned r = v.u + 0x7fffu + ((v.u >> 16) & 1u);
  return (ushort)(r >> 16);
}
__device__ __forceinline__ float bf2f(ushort u) {
  union { unsigned u; float f; } v; v.u = ((unsigned)u) << 16; return v.f;
}

__device__ __forceinline__ void gld16(const void* g, void* l) {
  __builtin_amdgcn_global_load_lds((const __attribute__((address_space(1))) void*)g,
                                   (__attribute__((address_space(3))) void*)l, 16, 0, 0);
}

// gelu, tanh-form via sigmoid: v * sigmoid(1.5957691(v + 0.044715 v^3))
// |err vs exact erf-gelu| ~1e-3, well below bf16 quantization of the FF buffer.
__device__ __forceinline__ float fast_gelu(float v) {
  float t2 = fmaf(v * v, 0.07135481283f, 1.5957691216f);
  float z  = v * t2;
  float e  = __expf(-z);
  return v * __builtin_amdgcn_rcpf(1.0f + e);
}

// ---------------------------------------------------------------------------
// y[b,t,d] = x[b,d,t] + pe0[t/64,d] + pe1[t%64,d]
// ---------------------------------------------------------------------------
__global__ __launch_bounds__(256)
void add_pos_k(const float* __restrict__ x, const float* __restrict__ pe0,
               const float* __restrict__ pe1, float* __restrict__ y) {
  __shared__ float tile[32][33];
  int b  = blockIdx.z;
  int t0 = blockIdx.x * 32;
  int d0 = blockIdx.y * 32;
  int tj = threadIdx.x;
  int di = threadIdx.y;
#pragma unroll
  for (int k = 0; k < 4; k++) {
    int d = d0 + di + k * 8;
    tile[di + k * 8][tj] = x[((size_t)b * DIMC + d) * T_LEN + t0 + tj];
  }
  __syncthreads();
#pragma unroll
  for (int k = 0; k < 4; k++) {
    int t = t0 + di + k * 8;
    int d = d0 + tj;
    y[((size_t)b * T_LEN + t) * DIMC + d] =
        tile[tj][di + k * 8] + pe0[(size_t)(t >> 6) * DIMC + d] + pe1[(size_t)(t & 63) * DIMC + d];
  }
}

// ---------------------------------------------------------------------------
// Standalone LayerNorm (layer-0 LN1 only). Writes bf16.
// ---------------------------------------------------------------------------
__global__ __launch_bounds__(256)
void layernorm_k(const float* __restrict__ x, const float* __restrict__ g,
                 const float* __restrict__ b, ushort* __restrict__ o) {
  int row  = blockIdx.x * 4 + (threadIdx.x >> 6);
  int lane = threadIdx.x & 63;
  const float4* xr = (const float4*)(x + (size_t)row * DIMC);
  float4 v = xr[lane];
  float s  = v.x + v.y + v.z + v.w;
  float s2 = v.x * v.x + v.y * v.y + v.z * v.z + v.w * v.w;
#pragma unroll
  for (int off = 32; off; off >>= 1) {
    s  += __shfl_xor(s, off);
    s2 += __shfl_xor(s2, off);
  }
  float mean = s * (1.0f / 256.0f);
  float var  = s2 * (1.0f / 256.0f) - mean * mean;
  float r    = rsqrtf(var + 1e-5f);
  float4 gv = ((const float4*)g)[lane];
  float4 bv = ((const float4*)b)[lane];
  ushort4 o4;
  o4.x = f2bf((v.x - mean) * r * gv.x + bv.x);
  o4.y = f2bf((v.y - mean) * r * gv.y + bv.y);
  o4.z = f2bf((v.z - mean) * r * gv.z + bv.z);
  o4.w = f2bf((v.w - mean) * r * gv.w + bv.w);
  ((ushort4*)(o + (size_t)row * DIMC))[lane] = o4;
}

// ---------------------------------------------------------------------------
// weight convert: Wt[l][n][k] = bf16(W[l][k][n])
// ---------------------------------------------------------------------------
__global__ __launch_bounds__(256)
void wt_bf16_k(const float* __restrict__ W, ushort* __restrict__ Wt,
               int K, int N, size_t outStride) {
  __shared__ float t[32][33];
  int l = blockIdx.z;
  const float* Wl = W + (size_t)l * K * N;
  ushort* Wtl = Wt + (size_t)l * outStride;
  int n0 = blockIdx.x * 32, k0 = blockIdx.y * 32;
  int tx = threadIdx.x, ty = threadIdx.y;
#pragma unroll
  for (int p = 0; p < 4; p++)
    t[ty + p * 8][tx] = Wl[(size_t)(k0 + ty + p * 8) * N + n0 + tx];
  __syncthreads();
#pragma unroll
  for (int p = 0; p < 4; p++)
    Wtl[(size_t)(n0 + ty + p * 8) * K + k0 + tx] = f2bf(t[tx][ty + p * 8]);
}

// ---------------------------------------------------------------------------
// bf16 MFMA GEMM: epi(A(MxK,lda) @ Bt(NxK,ldb)^T [+bias]) -> bf16
// EPI 0: store. EPI 1: gelu(.+bias).
// 128x128 tile, BK=32, 256 threads (2x2 waves), 4x4 MFMA per wave.
// LDS tiles are chunk-XOR swizzled (chunk ^= (row>>1)&3) to kill the 8-way
// bank conflict of 64B-stride row-major reads. Staging keeps the LDS dest
// linear (global_load_lds requirement) and pre-swizzles the GLOBAL source
// column; ds_read applies the same XOR (rule #21: both sides or neither).
// ---------------------------------------------------------------------------
template <int EPI>
__global__ __launch_bounds__(256)
void gemm_bf16(const ushort* __restrict__ A, const ushort* __restrict__ Bt,
               const float* __restrict__ bias, ushort* __restrict__ Cbf,
               int N, int K, int lda, int ldb) {
  __shared__ ushort As[128 * 32];
  __shared__ ushort Bs[128 * 32];
  __shared__ ushort eb[4][16][66];   // per-wave transpose buffer (pad 66)
  int tid = threadIdx.x;
  int w = tid >> 6, lane = tid & 63;
  int bm = blockIdx.x << 7, bn = blockIdx.y << 7;
  int wm = (w >> 1) << 6, wn = (w & 1) << 6;
  int l15 = lane & 15, quad = lane >> 4;

  int off0 = (w << 11) + (lane << 4);
  int off1 = off0 + 1024;
  int r0 = off0 >> 6;
  int r1 = off1 >> 6;
  // source-column swizzle: chunk = lane&3, s(row) = (lane>>3)&3 (same for r0,r1)
  int swc = (((lane & 3) ^ ((lane >> 3) & 3)) << 3);
  const ushort* ga0 = A + (size_t)(bm + r0) * lda + swc;
  const ushort* ga1 = A + (size_t)(bm + r1) * lda + swc;
  const ushort* gb0 = Bt + (size_t)(bn + r0) * ldb + swc;
  const ushort* gb1 = Bt + (size_t)(bn + r1) * ldb + swc;
  ushort* lA0 = As + (w << 10);
  ushort* lA1 = lA0 + 512;
  ushort* lB0 = Bs + (w << 10);
  ushort* lB1 = lB0 + 512;

  // read-side swizzled quad: s(row) = (l15>>1)&3  (wm, wn, i*16 are 0 mod 8 rows)
  int sq = quad ^ ((l15 >> 1) & 3);

  f32x4 acc[4][4];
#pragma unroll
  for (int i = 0; i < 4; i++)
#pragma unroll
    for (int j = 0; j < 4; j++) {
      f32x4 z = {0.f, 0.f, 0.f, 0.f};
      acc[i][j] = z;
    }

  for (int k0 = 0; k0 < K; k0 += 32) {
    gld16(ga0 + k0, lA0);
    gld16(ga1 + k0, lA1);
    gld16(gb0 + k0, lB0);
    gld16(gb1 + k0, lB1);
    __syncthreads();
    bf16x8 aF[4], bF[4];
#pragma unroll
    for (int i = 0; i < 4; i++)
      aF[i] = *(const bf16x8*)(As + ((wm + (i << 4) + l15) << 5) + (sq << 3));
#pragma unroll
    for (int j = 0; j < 4; j++)
      bF[j] = *(const bf16x8*)(Bs + ((wn + (j << 4) + l15) << 5) + (sq << 3));
#pragma unroll
    for (int i = 0; i < 4; i++)
#pragma unroll
      for (int j = 0; j < 4; j++)
        acc[i][j] = __builtin_amdgcn_mfma_f32_16x16x32_bf16(aF[i], bF[j], acc[i][j], 0, 0, 0);
    __syncthreads();
  }

  float bvj[4];
  if (EPI == 1) {
#pragma unroll
    for (int j = 0; j < 4; j++) bvj[j] = bias[bn + wn + (j << 4) + l15];
  }
#pragma unroll
  for (int i = 0; i < 4; i++) {
    // 16 rows x 64 cols -> per-wave LDS (wave-local, no barrier needed)
#pragma unroll
    for (int j = 0; j < 4; j++) {
#pragma unroll
      for (int r = 0; r < 4; r++) {
        float v = acc[i][j][r];
        if (EPI == 1) v = fast_gelu(v + bvj[j]);
        eb[w][(quad << 2) + r][(j << 4) + l15] = f2bf(v);
      }
    }
#pragma unroll
    for (int h = 0; h < 2; h++) {
      int chunk = (h << 6) + lane;          // 0..127
      int row = chunk >> 3, c8 = (chunk & 7) << 3;
      bf16x8 vv = *(const bf16x8*)&eb[w][row][c8];
      *(bf16x8*)&Cbf[(size_t)(bm + wm + (i << 4) + row) * N + bn + wn + c8] = vv;
    }
  }
}

// ---------------------------------------------------------------------------
// GEMM + bias + residual + LayerNorm. 64-row blocks (grid M/64), 256 threads.
// Waves 2x2: wave tile = 32 rows x 128 cols (2 aF x 8 bF = 16 MFMA / K-step).
// Same chunk-XOR LDS swizzle as gemm_bf16. Generic K (multiple of 32).
//   v = A@Bt^T + bias + y
//   FINAL=0: y = v ; obf = bf16(LN(v)) via LDS-transpose vector stores
//   FINAL=1: y = LN(v) (fp32 final)
// ---------------------------------------------------------------------------
template <int FINAL>
__global__ __launch_bounds__(256)
void oproj_ln_k(const ushort* __restrict__ A, const ushort* __restrict__ Bt,
                const float* __restrict__ bias, float* __restrict__ y,
                const float* __restrict__ g, const float* __restrict__ b,
                ushort* __restrict__ obf, int K, int lda) {
  // union: staging As(64x32) + Bs(256x32) = 10240 ushorts  |  eb 64x264 ushorts
  __shared__ ushort smem[64 * 264];
  __shared__ float red[2][64][2];
  __shared__ float stat[64][2];
  ushort* As = smem;            // 2048 ushorts
  ushort* Bs = smem + 2048;     // 8192 ushorts
  int tid = threadIdx.x;
  int wid = tid >> 6, lane = tid & 63;
  int l15 = lane & 15, quad = lane >> 4;
  int bm = blockIdx.x << 6;
  int wm = (wid >> 1) << 5;   // 0 / 32
  int wn = (wid & 1) << 7;    // 0 / 128

  // source-column swizzle: chunk = tid&3, s(row) = (tid>>3)&3 (A and all B pages)
  int swc = (((tid & 3) ^ ((tid >> 3) & 3)) << 3);
  // A staging: 64x32 bf16 = 4KB = 256 threads x 16B (1 issue)
  const ushort* gaA = A + (size_t)(bm + (tid >> 2)) * lda + swc;
  ushort* lA = As + (tid << 3);
  // B staging: 256x32 bf16 = 16KB = 4 issues
  const ushort* gaB[4];
  ushort* lB[4];
#pragma unroll
  for (int p = 0; p < 4; p++) {
    int u = (p << 8) + tid;
    gaB[p] = Bt + (size_t)(u >> 2) * K + swc;
    lB[p] = Bs + (u << 3);
  }

  int sq = quad ^ ((l15 >> 1) & 3);

  f32x4 acc[2][8];
#pragma unroll
  for (int i = 0; i < 2; i++)
#pragma unroll
    for (int j = 0; j < 8; j++) {
      f32x4 z = {0.f, 0.f, 0.f, 0.f};
      acc[i][j] = z;
    }

  for (int k0 = 0; k0 < K; k0 += 32) {
    gld16(gaA + k0, lA);
#pragma unroll
    for (int p = 0; p < 4; p++) gld16(gaB[p] + k0, lB[p]);
    __syncthreads();
    bf16x8 aF[2];
#pragma unroll
    for (int i = 0; i < 2; i++)
      aF[i] = *(const bf16x8*)(As + ((wm + (i << 4) + l15) << 5) + (sq << 3));
#pragma unroll
    for (int j = 0; j < 8; j++) {
      bf16x8 bF = *(const bf16x8*)(Bs + ((wn + (j << 4) + l15) << 5) + (sq << 3));
#pragma unroll
      for (int i = 0; i < 2; i++)
        acc[i][j] = __builtin_amdgcn_mfma_f32_16x16x32_bf16(aF[i], bF, acc[i][j], 0, 0, 0);
    }
    __syncthreads();
  }

  // epilogue: bias + residual (+ y store), per-row stats
  float bc[8];
#pragma unroll
  for (int j = 0; j < 8; j++) bc[j] = bias[wn + (j << 4) + l15];
  float s1v[2][4], s2v[2][4];
#pragma unroll
  for (int i = 0; i < 2; i++)
#pragma unroll
    for (int r = 0; r < 4; r++) {
      int row = bm + wm + (i << 4) + (quad << 2) + r;
      float s1 = 0.f, s2 = 0.f;
#pragma unroll
      for (int j = 0; j < 8; j++) {
        size_t idx = (size_t)row * 256 + wn + (j << 4) + l15;
        float v = acc[i][j][r] + bc[j] + y[idx];
        acc[i][j][r] = v;
        if (!FINAL) y[idx] = v;
        s1 += v;
        s2 += v * v;
      }
      s1v[i][r] = s1;
      s2v[i][r] = s2;
    }
#pragma unroll
  for (int off = 1; off < 16; off <<= 1)
#pragma unroll
    for (int i = 0; i < 2; i++)
#pragma unroll
      for (int r = 0; r < 4; r++) {
        s1v[i][r] += __shfl_xor(s1v[i][r], off);
        s2v[i][r] += __shfl_xor(s2v[i][r], off);
      }
  if (l15 == 0) {
#pragma unroll
    for (int i = 0; i < 2; i++)
#pragma unroll
      for (int r = 0; r < 4; r++) {
        int lr = wm + (i << 4) + (quad << 2) + r;
        red[wid & 1][lr][0] = s1v[i][r];
        red[wid & 1][lr][1] = s2v[i][r];
      }
  }
  __syncthreads();
  if (tid < 64) {
    float s  = red[0][tid][0] + red[1][tid][0];
    float s2 = red[0][tid][1] + red[1][tid][1];
    float mean = s * (1.0f / 256.0f);
    float var  = s2 * (1.0f / 256.0f) - mean * mean;
    stat[tid][0] = mean;
    stat[tid][1] = rsqrtf(var + 1e-5f);
  }
  __syncthreads();

  if (FINAL) {
#pragma unroll
    for (int j = 0; j < 8; j++) {
      int col = wn + (j << 4) + l15;
      float gc = g[col], bc2 = b[col];
#pragma unroll
      for (int i = 0; i < 2; i++)
#pragma unroll
        for (int r = 0; r < 4; r++) {
          int lr = wm + (i << 4) + (quad << 2) + r;
          float o = (acc[i][j][r] - stat[lr][0]) * stat[lr][1] * gc + bc2;
          y[(size_t)(bm + lr) * 256 + col] = o;
        }
    }
  } else {
    // LN -> LDS transpose buffer (64 x 264 pad) -> bf16x8 coalesced stores
    ushort (*eb)[264] = (ushort(*)[264])smem;
#pragma unroll
    for (int j = 0; j < 8; j++) {
      int col = wn + (j << 4) + l15;
      float gc = g[col], bc2 = b[col];
#pragma unroll
      for (int i = 0; i < 2; i++)
#pragma unroll
        for (int r = 0; r < 4; r++) {
          int lr = wm + (i << 4) + (quad << 2) + r;
          float o = (acc[i][j][r] - stat[lr][0]) * stat[lr][1] * gc + bc2;
          eb[lr][col] = f2bf(o);
        }
    }
    __syncthreads();
#pragma unroll
    for (int h = 0; h < 8; h++) {
      int chunk = (h << 8) + tid;           // 0..2047
      int row = chunk >> 5, c8 = (chunk & 31) << 3;
      bf16x8 vv = *(const bf16x8*)&eb[row][c8];
      *(bf16x8*)&obf[(size_t)(bm + row) * 256 + c8] = vv;
    }
  }
}

// ---------------------------------------------------------------------------
// bucket summaries from packed qkv (ld 768): q at +0, k at +256
// ---------------------------------------------------------------------------
__global__ __launch_bounds__(64)
void summary_k(const ushort* __restrict__ qkv,
               float* __restrict__ sq, float* __restrict__ sk) {
  int blk = blockIdx.x;
  int bh = blk >> 7, ib = blk & 127;
  int b = bh >> 3, h = bh & 7;
  int lane = threadIdx.x;
  int d = lane & 31;
  bool isK = lane >= 32;
  size_t base = ((size_t)b * T_LEN + (size_t)ib * 64) * 768 + (isK ? 256 : 0) + h * 32 + d;
  float s = 0.f;
#pragma unroll 8
  for (int t = 0; t < 64; t++) s += bf2f(qkv[base + (size_t)t * 768]);
  s *= (1.0f / 64.0f);
  float* dst = isK ? sk : sq;
  dst[((size_t)bh * NBUCK + ib) * 32 + d] = s;
}

// ---------------------------------------------------------------------------
// routing
// ---------------------------------------------------------------------------
__global__ __launch_bounds__(64)
void route_k(const float* __restrict__ sq, const float* __restrict__ sk,
             int* __restrict__ ridx, float* __restrict__ rw) {
  int blk = blockIdx.x;
  int bh = blk >> 7, ib = blk & 127;
  int lane = threadIdx.x;
  const float* qrow = sq + ((size_t)bh * NBUCK + ib) * 32;
  const float* k0 = sk + ((size_t)bh * NBUCK + lane) * 32;
  const float* k1 = k0 + 64 * 32;
  float s0 = 0.f, s1 = 0.f;
#pragma unroll
  for (int d = 0; d < 32; d++) {
    float qd = qrow[d];
    s0 += qd * k0[d];
    s1 += qd * k1[d];
  }
  const float sc = 0.17677669529663687f * (4.0f / 3.0f);
  float L0 = s0 * sc, L1 = s1 * sc;
  float m = fmaxf(L0, L1);
#pragma unroll
  for (int off = 32; off; off >>= 1) m = fmaxf(m, __shfl_xor(m, off));
  float Z = expf(L0 - m) + expf(L1 - m);
#pragma unroll
  for (int off = 32; off; off >>= 1) Z += __shfl_xor(Z, off);
  float mv = (L1 > L0) ? L1 : L0;
  int mj = (L1 > L0) ? lane + 64 : lane;
#pragma unroll
  for (int off = 32; off; off >>= 1) {
    float ov = __shfl_xor(mv, off);
    int oj = __shfl_xor(mj, off);
    if (ov > mv || (ov == mv && oj < mj)) { mv = ov; mj = oj; }
  }
  if (lane == 0) {
    ridx[blk] = mj;
    rw[blk] = 1.0f / Z;
  }
}

// ---------------------------------------------------------------------------
// MFMA bucketed attention reading packed qkv (ld 768). Output bf16.
// ---------------------------------------------------------------------------
__global__ __launch_bounds__(256)
void attn_mfma_k(const ushort* __restrict__ qkv,
                 const int* __restrict__ ridx, const float* __restrict__ rw,
                 ushort* __restrict__ o) {
  __shared__ ushort Qs[64][40];
  __shared__ ushort Ks[128][40];
  __shared__ ushort Vt[32][136];
  __shared__ ushort Ps[4][16][136];
  int blk = blockIdx.x;
  int bh = blk >> 7, ib = blk & 127;
  int b = bh >> 3, h = bh & 7;
  int tid = threadIdx.x;
  int jr = ridx[blk];
  float w = rw[blk];
  {
    int r = tid >> 2, c = (tid & 3) << 3;
    const ushort* src = qkv + ((size_t)b * T_LEN + (size_t)ib * 64 + r) * 768 + h * 32 + c;
    *(bf16x8*)&Qs[r][c] = *(const bf16x8*)src;
  }
#pragma unroll
  for (int p = 0; p < 2; p++) {
    int idx = tid + (p << 8);
    int r = idx >> 2, c = (idx & 3) << 3;
    int srcb = (r < 64) ? jr : ib;
    int tt = r & 63;
    const ushort* src = qkv + ((size_t)b * T_LEN + (size_t)srcb * 64 + tt) * 768 + 256 + h * 32 + c;
    *(bf16x8*)&Ks[r][c] = *(const bf16x8*)src;
  }
  {
    int tok = tid >> 1, d0 = (tid & 1) << 4;
    int srcb = (tok < 64) ? jr : ib;
    int tt = tok & 63;
    const ushort* src = qkv + ((size_t)b * T_LEN + (size_t)srcb * 64 + tt) * 768 + 512 + h * 32 + d0;
    bf16x8 v0 = *(const bf16x8*)src;
    bf16x8 v1 = *(const bf16x8*)(src + 8);
#pragma unroll
    for (int j = 0; j < 8; j++) {
      Vt[d0 + j][tok] = (ushort)v0[j];
      Vt[d0 + 8 + j][tok] = (ushort)v1[j];
    }
  }
  __syncthreads();
  int wid = tid >> 6, lane = tid & 63, l15 = lane & 15, quad = lane >> 4;
  bf16x8 aQ = *(const bf16x8*)&Qs[(wid << 4) + l15][quad << 3];
  f32x4 sf[8];
#pragma unroll
  for (int jn = 0; jn < 8; jn++) {
    bf16x8 bK = *(const bf16x8*)&Ks[(jn << 4) + l15][quad << 3];
    f32x4 z = {0.f, 0.f, 0.f, 0.f};
    sf[jn] = __builtin_amdgcn_mfma_f32_16x16x32_bf16(aQ, bK, z, 0, 0, 0);
  }
  const float sc = 0.17677669529663687f;
#pragma unroll
  for (int jn = 0; jn < 8; jn++) {
    float mult = (jn < 4) ? w * sc : sc;
#pragma unroll
    for (int r = 0; r < 4; r++) sf[jn][r] *= mult;
  }
  float mx[4], sm[4], inv[4];
#pragma unroll
  for (int r = 0; r < 4; r++) {
    float m = sf[0][r];
#pragma unroll
    for (int jn = 1; jn < 8; jn++) m = fmaxf(m, sf[jn][r]);
    mx[r] = m;
  }
#pragma unroll
  for (int off = 1; off < 16; off <<= 1)
#pragma unroll
    for (int r = 0; r < 4; r++) mx[r] = fmaxf(mx[r], __shfl_xor(mx[r], off));
#pragma unroll
  for (int r = 0; r < 4; r++) sm[r] = 0.f;
#pragma unroll
  for (int jn = 0; jn < 8; jn++)
#pragma unroll
    for (int r = 0; r < 4; r++) {
      sf[jn][r] = __expf(sf[jn][r] - mx[r]);
      sm[r] += sf[jn][r];
    }
#pragma unroll
  for (int off = 1; off < 16; off <<= 1)
#pragma unroll
    for (int r = 0; r < 4; r++) sm[r] += __shfl_xor(sm[r], off);
#pragma unroll
  for (int r = 0; r < 4; r++) inv[r] = __builtin_amdgcn_rcpf(sm[r]);
#pragma unroll
  for (int jn = 0; jn < 8; jn++) {
    float ws2 = (jn < 4) ? w : 1.f;
#pragma unroll
    for (int r = 0; r < 4; r++)
      Ps[wid][(quad << 2) + r][(jn << 4) + l15] = f2bf(sf[jn][r] * inv[r] * ws2);
  }
  f32x4 of[2];
#pragma unroll
  for (int nd = 0; nd < 2; nd++) { f32x4 z = {0.f, 0.f, 0.f, 0.f}; of[nd] = z; }
#pragma unroll
  for (int kk = 0; kk < 4; kk++) {
    bf16x8 aP = *(const bf16x8*)&Ps[wid][l15][(kk << 5) + (quad << 3)];
#pragma unroll
    for (int nd = 0; nd < 2; nd++) {
      bf16x8 bV = *(const bf16x8*)&Vt[(nd << 4) + l15][(kk << 5) + (quad << 3)];
      of[nd] = __builtin_amdgcn_mfma_f32_16x16x32_bf16(aP, bV, of[nd], 0, 0, 0);
    }
  }
  ushort* obase = o + ((size_t)b * T_LEN + (size_t)ib * 64 + (wid << 4) + (quad << 2)) * 256 + h * 32 + l15;
#pragma unroll
  for (int nd = 0; nd < 2; nd++)
#pragma unroll
    for (int r = 0; r < 4; r++)
      obase[(size_t)r * 256 + (nd << 4)] = f2bf(of[nd][r]);
}

// ---------------------------------------------------------------------------
// out[b,d,t] = yln[b,t,d]
// ---------------------------------------------------------------------------
__global__ __launch_bounds__(256)
void transpose_out_k(const float* __restrict__ yln, float* __restrict__ out) {
  __shared__ float tile[32][33];
  int b  = blockIdx.z;
  int t0 = blockIdx.x * 32;
  int d0 = blockIdx.y * 32;
  int tx = threadIdx.x;
  int ty = threadIdx.y;
#pragma unroll
  for (int k = 0; k < 4; k++) {
    int t = t0 + ty + k * 8;
    tile[ty + k * 8][tx] = yln[((size_t)b * T_LEN + t) * DIMC + d0 + tx];
  }
  __syncthreads();
#pragma unroll
  for (int k = 0; k < 4; k++) {
    int d = d0 + ty + k * 8;
    out[((size_t)b * DIMC + d) * T_LEN + t0 + tx] = tile[tx][ty + k * 8];
  }
}

// ---------------------------------------------------------------------------
extern "C" void kernel_launch(void* const* d_in, const int* in_sizes, int n_in,
                              void* d_out, int out_size, void* d_ws, size_t ws_size,
                              hipStream_t stream) {
  const float* x     = (const float*)d_in[0];
  const float* pe0   = (const float*)d_in[1];
  const float* pe1   = (const float*)d_in[2];
  const float* ln1_g = (const float*)d_in[3];
  const float* ln1_b = (const float*)d_in[4];
  const float* Wq    = (const float*)d_in[5];
  const float* Wkv   = (const float*)d_in[6];
  const float* Wo    = (const float*)d_in[7];
  const float* bo    = (const float*)d_in[8];
  const float* ln2_g = (const float*)d_in[9];
  const float* ln2_b = (const float*)d_in[10];
  const float* W1    = (const float*)d_in[11];
  const float* b1    = (const float*)d_in[12];
  const float* W2    = (const float*)d_in[13];
  const float* b2    = (const float*)d_in[14];
  const float* gf    = (const float*)d_in[15];
  const float* bfp   = (const float*)d_in[16];
  float* out = (float*)d_out;

  const int M = MROWS;
  float*  y    = (float*)d_ws;                       // M*256 f32
  ushort* qkv  = (ushort*)(y + (size_t)M * 256);     // M*768 bf16
  ushort* bufA = qkv + (size_t)M * 768;              // attn out (bf16)
  ushort* bufB = bufA + (size_t)M * 256;             // LN out (bf16)
  ushort* wbf  = bufB + (size_t)M * 256;             // 6*786432 transposed weights
  float*  sqb  = (float*)(wbf + (size_t)6 * 786432);
  float*  skb  = sqb + 131072;
  float*  rwb  = skb + 131072;
  int*    rib  = (int*)(rwb + 4096);
  ushort* ffbf = qkv;   // FF intermediate (M*1024) overlays dead qkv+bufA

  dim3 tb(32, 8);
  wt_bf16_k<<<dim3(8, 8, 6),  tb, 0, stream>>>(Wq,  wbf + 0,      256, 256,  786432);
  wt_bf16_k<<<dim3(16, 8, 6), tb, 0, stream>>>(Wkv, wbf + 65536,  256, 512,  786432);
  wt_bf16_k<<<dim3(8, 8, 6),  tb, 0, stream>>>(Wo,  wbf + 196608, 256, 256,  786432);
  wt_bf16_k<<<dim3(32, 8, 6), tb, 0, stream>>>(W1,  wbf + 262144, 256, 1024, 786432);
  wt_bf16_k<<<dim3(8, 32, 6), tb, 0, stream>>>(W2,  wbf + 524288, 1024, 256, 786432);

  add_pos_k<<<dim3(T_LEN / 32, DIMC / 32, 4), tb, 0, stream>>>(x, pe0, pe1, y);
  layernorm_k<<<M / 4, 256, 0, stream>>>(y, ln1_g, ln1_b, bufB);   // layer-0 LN1

  for (int l = 0; l < 6; l++) {
    const ushort* wl    = wbf + (size_t)l * 786432;
    const ushort* wqkvT = wl;
    const ushort* woT   = wl + 196608;
    const ushort* w1T   = wl + 262144;
    const ushort* w2T   = wl + 524288;

    gemm_bf16<0><<<dim3(M / 128, 6), 256, 0, stream>>>(bufB, wqkvT, nullptr, qkv, 768, 256, 256, 256);
    summary_k<<<BHEAD * NBUCK, 64, 0, stream>>>(qkv, sqb, skb);
    route_k<<<BHEAD * NBUCK, 64, 0, stream>>>(sqb, skb, rib, rwb);
    attn_mfma_k<<<BHEAD * NBUCK, 256, 0, stream>>>(qkv, rib, rwb, bufA);
    // o-proj + bias + residual + LN2 -> bufB (K=256)
    oproj_ln_k<0><<<M / 64, 256, 0, stream>>>(bufA, woT, bo + l * 256, y,
                                              ln2_g + l * 256, ln2_b + l * 256,
                                              bufB, 256, 256);
    // FF1 + gelu -> ffbf (overlays dead qkv+bufA)
    gemm_bf16<1><<<dim3(M / 128, 8), 256, 0, stream>>>(bufB, w1T, b1 + l * 1024, ffbf, 1024, 256, 256, 256);
    // FF2 + bias + residual + LN (next LN1 / final LN), K=1024
    if (l < 5) {
      oproj_ln_k<0><<<M / 64, 256, 0, stream>>>(ffbf, w2T, b2 + l * 256, y,
                                                ln1_g + (l + 1) * 256, ln1_b + (l + 1) * 256,
                                                bufB, 1024, 1024);
    } else {
      oproj_ln_k<1><<<M / 64, 256, 0, stream>>>(ffbf, w2T, b2 + l * 256, y,
                                                gf, bfp, nullptr, 1024, 1024);
    }
  }

  transpose_out_k<<<dim3(T_LEN / 32, DIMC / 32, 4), tb, 0, stream>>>(y, out);

  (void)in_sizes; (void)n_in; (void)out_size; (void)ws_size;
}

// Round 4
// 1123.996 us; speedup vs baseline: 1.2216x; 1.0383x over previous
//
#include <hip/hip_runtime.h>
#include <cstdint>
#include <cstddef>

#define T_LEN 8192
#define DIMC  256
#define NBUCK 128
#define BHEAD 32
#define MROWS 32768

typedef __attribute__((ext_vector_type(8))) short bf16x8;
typedef __attribute__((ext_vector_type(4))) float f32x4;

__device__ __forceinline__ ushort f2bf(float x) {
  union { float f; unsigned u; } v; v.f = x;
  unsigned r = v.u + 0x7fffu + ((v.u >> 16) & 1u);
  return (ushort)(r >> 16);
}
__device__ __forceinline__ float bf2f(ushort u) {
  union { unsigned u; float f; } v; v.u = ((unsigned)u) << 16; return v.f;
}

__device__ __forceinline__ void gld16(const void* g, void* l) {
  __builtin_amdgcn_global_load_lds((const __attribute__((address_space(1))) void*)g,
                                   (__attribute__((address_space(3))) void*)l, 16, 0, 0);
}

// gelu, tanh-form via sigmoid: v * sigmoid(1.5957691(v + 0.044715 v^3))
// |err vs exact erf-gelu| ~1e-3, well below bf16 quantization of the FF buffer.
__device__ __forceinline__ float fast_gelu(float v) {
  float t2 = fmaf(v * v, 0.07135481283f, 1.5957691216f);
  float z  = v * t2;
  float e  = __expf(-z);
  return v * __builtin_amdgcn_rcpf(1.0f + e);
}

// ---------------------------------------------------------------------------
// y[b,t,d] = x[b,d,t] + pe0[t/64,d] + pe1[t%64,d]
// ---------------------------------------------------------------------------
__global__ __launch_bounds__(256)
void add_pos_k(const float* __restrict__ x, const float* __restrict__ pe0,
               const float* __restrict__ pe1, float* __restrict__ y) {
  __shared__ float tile[32][33];
  int b  = blockIdx.z;
  int t0 = blockIdx.x * 32;
  int d0 = blockIdx.y * 32;
  int tj = threadIdx.x;
  int di = threadIdx.y;
#pragma unroll
  for (int k = 0; k < 4; k++) {
    int d = d0 + di + k * 8;
    tile[di + k * 8][tj] = x[((size_t)b * DIMC + d) * T_LEN + t0 + tj];
  }
  __syncthreads();
#pragma unroll
  for (int k = 0; k < 4; k++) {
    int t = t0 + di + k * 8;
    int d = d0 + tj;
    y[((size_t)b * T_LEN + t) * DIMC + d] =
        tile[tj][di + k * 8] + pe0[(size_t)(t >> 6) * DIMC + d] + pe1[(size_t)(t & 63) * DIMC + d];
  }
}

// ---------------------------------------------------------------------------
// Standalone LayerNorm (layer-0 LN1 only). Writes bf16.
// ---------------------------------------------------------------------------
__global__ __launch_bounds__(256)
void layernorm_k(const float* __restrict__ x, const float* __restrict__ g,
                 const float* __restrict__ b, ushort* __restrict__ o) {
  int row  = blockIdx.x * 4 + (threadIdx.x >> 6);
  int lane = threadIdx.x & 63;
  const float4* xr = (const float4*)(x + (size_t)row * DIMC);
  float4 v = xr[lane];
  float s  = v.x + v.y + v.z + v.w;
  float s2 = v.x * v.x + v.y * v.y + v.z * v.z + v.w * v.w;
#pragma unroll
  for (int off = 32; off; off >>= 1) {
    s  += __shfl_xor(s, off);
    s2 += __shfl_xor(s2, off);
  }
  float mean = s * (1.0f / 256.0f);
  float var  = s2 * (1.0f / 256.0f) - mean * mean;
  float r    = rsqrtf(var + 1e-5f);
  float4 gv = ((const float4*)g)[lane];
  float4 bv = ((const float4*)b)[lane];
  ushort4 o4;
  o4.x = f2bf((v.x - mean) * r * gv.x + bv.x);
  o4.y = f2bf((v.y - mean) * r * gv.y + bv.y);
  o4.z = f2bf((v.z - mean) * r * gv.z + bv.z);
  o4.w = f2bf((v.w - mean) * r * gv.w + bv.w);
  ((ushort4*)(o + (size_t)row * DIMC))[lane] = o4;
}

// ---------------------------------------------------------------------------
// weight convert: Wt[l][n][k] = bf16(W[l][k][n])
// ---------------------------------------------------------------------------
__global__ __launch_bounds__(256)
void wt_bf16_k(const float* __restrict__ W, ushort* __restrict__ Wt,
               int K, int N, size_t outStride) {
  __shared__ float t[32][33];
  int l = blockIdx.z;
  const float* Wl = W + (size_t)l * K * N;
  ushort* Wtl = Wt + (size_t)l * outStride;
  int n0 = blockIdx.x * 32, k0 = blockIdx.y * 32;
  int tx = threadIdx.x, ty = threadIdx.y;
#pragma unroll
  for (int p = 0; p < 4; p++)
    t[ty + p * 8][tx] = Wl[(size_t)(k0 + ty + p * 8) * N + n0 + tx];
  __syncthreads();
#pragma unroll
  for (int p = 0; p < 4; p++)
    Wtl[(size_t)(n0 + ty + p * 8) * K + k0 + tx] = f2bf(t[tx][ty + p * 8]);
}

// ---------------------------------------------------------------------------
// bf16 MFMA GEMM: epi(A(MxK,lda) @ Bt(NxK,ldb)^T [+bias]) -> bf16
// EPI 0: store. EPI 1: gelu(.+bias).
// 128x128 tile, BK=32, 256 threads (2x2 waves), 4x4 MFMA per wave.
// Double-buffered LDS staging (2-phase): next K-slab's global_load_lds is
// issued BEFORE computing the current slab, so the vmcnt(0) drain folded into
// the single trailing barrier waits on loads whose latency was hidden by
// 16 ds_reads + 16 MFMAs. Chunk-XOR swizzle (rule #21, both sides) retained.
// ---------------------------------------------------------------------------
template <int EPI>
__global__ __launch_bounds__(256)
void gemm_bf16(const ushort* __restrict__ A, const ushort* __restrict__ Bt,
               const float* __restrict__ bias, ushort* __restrict__ Cbf,
               int N, int K, int lda, int ldb) {
  // 2 buffers x (As 4096 + Bs 4096) ushorts = 32 KB. eb overlays buffer 0.
  __shared__ ushort sm[2][8192];
  int tid = threadIdx.x;
  int w = tid >> 6, lane = tid & 63;
  int bm = blockIdx.x << 7, bn = blockIdx.y << 7;
  int wm = (w >> 1) << 6, wn = (w & 1) << 6;
  int l15 = lane & 15, quad = lane >> 4;

  int off0 = (w << 11) + (lane << 4);   // byte offset within an 8KB tile
  int r0 = off0 >> 6;
  int r1 = (off0 + 1024) >> 6;
  // source-column swizzle: chunk = lane&3, s(row) = (lane>>3)&3 (same for r0,r1)
  int swc = (((lane & 3) ^ ((lane >> 3) & 3)) << 3);
  const ushort* ga0 = A + (size_t)(bm + r0) * lda + swc;
  const ushort* ga1 = A + (size_t)(bm + r1) * lda + swc;
  const ushort* gb0 = Bt + (size_t)(bn + r0) * ldb + swc;
  const ushort* gb1 = Bt + (size_t)(bn + r1) * ldb + swc;
  int aoff0 = (w << 10) + 0;      // ushort offsets within buffer
  int aoff1 = aoff0 + 512;
  int boff0 = 4096 + (w << 10);
  int boff1 = boff0 + 512;

  // read-side swizzled quad: s(row) = (l15>>1)&3
  int sq = quad ^ ((l15 >> 1) & 3);

  f32x4 acc[4][4];
#pragma unroll
  for (int i = 0; i < 4; i++)
#pragma unroll
    for (int j = 0; j < 4; j++) {
      f32x4 z = {0.f, 0.f, 0.f, 0.f};
      acc[i][j] = z;
    }

  // prologue: stage k0=0 into buffer 0
  gld16(ga0, &sm[0][aoff0]);
  gld16(ga1, &sm[0][aoff1]);
  gld16(gb0, &sm[0][boff0]);
  gld16(gb1, &sm[0][boff1]);
  __syncthreads();

  int cur = 0;
  for (int k0 = 0; k0 < K; k0 += 32) {
    if (k0 + 32 < K) {
      ushort* S = sm[cur ^ 1];
      gld16(ga0 + k0 + 32, S + aoff0);
      gld16(ga1 + k0 + 32, S + aoff1);
      gld16(gb0 + k0 + 32, S + boff0);
      gld16(gb1 + k0 + 32, S + boff1);
    }
    const ushort* Sc = sm[cur];
    bf16x8 aF[4], bF[4];
#pragma unroll
    for (int i = 0; i < 4; i++)
      aF[i] = *(const bf16x8*)(Sc + ((wm + (i << 4) + l15) << 5) + (sq << 3));
#pragma unroll
    for (int j = 0; j < 4; j++)
      bF[j] = *(const bf16x8*)(Sc + 4096 + ((wn + (j << 4) + l15) << 5) + (sq << 3));
#pragma unroll
    for (int i = 0; i < 4; i++)
#pragma unroll
      for (int j = 0; j < 4; j++)
        acc[i][j] = __builtin_amdgcn_mfma_f32_16x16x32_bf16(aF[i], bF[j], acc[i][j], 0, 0, 0);
    __syncthreads();
    cur ^= 1;
  }

  // epilogue transpose buffer overlays the (dead) staging LDS
  ushort (*eb)[16][66] = (ushort(*)[16][66])&sm[0][0];   // 4x16x66 = 4224 ushorts
  float bvj[4];
  if (EPI == 1) {
#pragma unroll
    for (int j = 0; j < 4; j++) bvj[j] = bias[bn + wn + (j << 4) + l15];
  }
#pragma unroll
  for (int i = 0; i < 4; i++) {
    // 16 rows x 64 cols -> per-wave LDS (wave-local, no barrier needed)
#pragma unroll
    for (int j = 0; j < 4; j++) {
#pragma unroll
      for (int r = 0; r < 4; r++) {
        float v = acc[i][j][r];
        if (EPI == 1) v = fast_gelu(v + bvj[j]);
        eb[w][(quad << 2) + r][(j << 4) + l15] = f2bf(v);
      }
    }
#pragma unroll
    for (int h = 0; h < 2; h++) {
      int chunk = (h << 6) + lane;          // 0..127
      int row = chunk >> 3, c8 = (chunk & 7) << 3;
      bf16x8 vv = *(const bf16x8*)&eb[w][row][c8];
      *(bf16x8*)&Cbf[(size_t)(bm + wm + (i << 4) + row) * N + bn + wn + c8] = vv;
    }
  }
}

// ---------------------------------------------------------------------------
// GEMM + bias + residual + LayerNorm. 64-row blocks (grid M/64), 256 threads.
// Waves 2x2: wave tile = 32 rows x 128 cols (2 aF x 8 bF = 16 MFMA / K-step).
// Double-buffered staging (2-phase) + chunk-XOR swizzle. Generic K (mult 32).
//   v = A@Bt^T + bias + y
//   FINAL=0: y = v ; obf = bf16(LN(v)) via LDS-transpose vector stores
//   FINAL=1: y = LN(v) (fp32 final)
// ---------------------------------------------------------------------------
template <int FINAL>
__global__ __launch_bounds__(256)
void oproj_ln_k(const ushort* __restrict__ A, const ushort* __restrict__ Bt,
                const float* __restrict__ bias, float* __restrict__ y,
                const float* __restrict__ g, const float* __restrict__ b,
                ushort* __restrict__ obf, int K, int lda) {
  // 2 buffers x (As 2048 + Bs 8192) ushorts = 40 KB. eb (64x264=16896) overlays.
  __shared__ ushort smem[20480];
  __shared__ float red[2][64][2];
  __shared__ float stat[64][2];
  int tid = threadIdx.x;
  int wid = tid >> 6, lane = tid & 63;
  int l15 = lane & 15, quad = lane >> 4;
  int bm = blockIdx.x << 6;
  int wm = (wid >> 1) << 5;   // 0 / 32
  int wn = (wid & 1) << 7;    // 0 / 128

  // source-column swizzle: chunk = tid&3, s(row) = (tid>>3)&3 (A and all B pages)
  int swc = (((tid & 3) ^ ((tid >> 3) & 3)) << 3);
  const ushort* gaA = A + (size_t)(bm + (tid >> 2)) * lda + swc;
  const ushort* gaB[4];
#pragma unroll
  for (int p = 0; p < 4; p++) {
    int u = (p << 8) + tid;
    gaB[p] = Bt + (size_t)(u >> 2) * K + swc;
  }
  int lAoff = tid << 3;                        // ushort offset in buffer
  int lBoff[4];
#pragma unroll
  for (int p = 0; p < 4; p++) lBoff[p] = 2048 + (((p << 8) + tid) << 3);

  int sq = quad ^ ((l15 >> 1) & 3);

  f32x4 acc[2][8];
#pragma unroll
  for (int i = 0; i < 2; i++)
#pragma unroll
    for (int j = 0; j < 8; j++) {
      f32x4 z = {0.f, 0.f, 0.f, 0.f};
      acc[i][j] = z;
    }

  // prologue: stage k0=0 into buffer 0
  gld16(gaA, smem + lAoff);
#pragma unroll
  for (int p = 0; p < 4; p++) gld16(gaB[p], smem + lBoff[p]);
  __syncthreads();

  int cur = 0;
  for (int k0 = 0; k0 < K; k0 += 32) {
    if (k0 + 32 < K) {
      ushort* S = smem + ((cur ^ 1) ? 10240 : 0);
      gld16(gaA + k0 + 32, S + lAoff);
#pragma unroll
      for (int p = 0; p < 4; p++) gld16(gaB[p] + k0 + 32, S + lBoff[p]);
    }
    const ushort* Sc = smem + (cur ? 10240 : 0);
    bf16x8 aF[2];
#pragma unroll
    for (int i = 0; i < 2; i++)
      aF[i] = *(const bf16x8*)(Sc + ((wm + (i << 4) + l15) << 5) + (sq << 3));
#pragma unroll
    for (int j = 0; j < 8; j++) {
      bf16x8 bF = *(const bf16x8*)(Sc + 2048 + ((wn + (j << 4) + l15) << 5) + (sq << 3));
#pragma unroll
      for (int i = 0; i < 2; i++)
        acc[i][j] = __builtin_amdgcn_mfma_f32_16x16x32_bf16(aF[i], bF, acc[i][j], 0, 0, 0);
    }
    __syncthreads();
    cur ^= 1;
  }

  // epilogue: bias + residual (+ y store), per-row stats
  float bc[8];
#pragma unroll
  for (int j = 0; j < 8; j++) bc[j] = bias[wn + (j << 4) + l15];
  float s1v[2][4], s2v[2][4];
#pragma unroll
  for (int i = 0; i < 2; i++)
#pragma unroll
    for (int r = 0; r < 4; r++) {
      int row = bm + wm + (i << 4) + (quad << 2) + r;
      float s1 = 0.f, s2 = 0.f;
#pragma unroll
      for (int j = 0; j < 8; j++) {
        size_t idx = (size_t)row * 256 + wn + (j << 4) + l15;
        float v = acc[i][j][r] + bc[j] + y[idx];
        acc[i][j][r] = v;
        if (!FINAL) y[idx] = v;
        s1 += v;
        s2 += v * v;
      }
      s1v[i][r] = s1;
      s2v[i][r] = s2;
    }
#pragma unroll
  for (int off = 1; off < 16; off <<= 1)
#pragma unroll
    for (int i = 0; i < 2; i++)
#pragma unroll
      for (int r = 0; r < 4; r++) {
        s1v[i][r] += __shfl_xor(s1v[i][r], off);
        s2v[i][r] += __shfl_xor(s2v[i][r], off);
      }
  if (l15 == 0) {
#pragma unroll
    for (int i = 0; i < 2; i++)
#pragma unroll
      for (int r = 0; r < 4; r++) {
        int lr = wm + (i << 4) + (quad << 2) + r;
        red[wid & 1][lr][0] = s1v[i][r];
        red[wid & 1][lr][1] = s2v[i][r];
      }
  }
  __syncthreads();
  if (tid < 64) {
    float s  = red[0][tid][0] + red[1][tid][0];
    float s2 = red[0][tid][1] + red[1][tid][1];
    float mean = s * (1.0f / 256.0f);
    float var  = s2 * (1.0f / 256.0f) - mean * mean;
    stat[tid][0] = mean;
    stat[tid][1] = rsqrtf(var + 1e-5f);
  }
  __syncthreads();

  if (FINAL) {
#pragma unroll
    for (int j = 0; j < 8; j++) {
      int col = wn + (j << 4) + l15;
      float gc = g[col], bc2 = b[col];
#pragma unroll
      for (int i = 0; i < 2; i++)
#pragma unroll
        for (int r = 0; r < 4; r++) {
          int lr = wm + (i << 4) + (quad << 2) + r;
          float o = (acc[i][j][r] - stat[lr][0]) * stat[lr][1] * gc + bc2;
          y[(size_t)(bm + lr) * 256 + col] = o;
        }
    }
  } else {
    // LN -> LDS transpose buffer (64 x 264 pad, overlays staging) -> bf16x8 stores
    ushort (*eb)[264] = (ushort(*)[264])smem;
#pragma unroll
    for (int j = 0; j < 8; j++) {
      int col = wn + (j << 4) + l15;
      float gc = g[col], bc2 = b[col];
#pragma unroll
      for (int i = 0; i < 2; i++)
#pragma unroll
        for (int r = 0; r < 4; r++) {
          int lr = wm + (i << 4) + (quad << 2) + r;
          float o = (acc[i][j][r] - stat[lr][0]) * stat[lr][1] * gc + bc2;
          eb[lr][col] = f2bf(o);
        }
    }
    __syncthreads();
#pragma unroll
    for (int h = 0; h < 8; h++) {
      int chunk = (h << 8) + tid;           // 0..2047
      int row = chunk >> 5, c8 = (chunk & 31) << 3;
      bf16x8 vv = *(const bf16x8*)&eb[row][c8];
      *(bf16x8*)&obf[(size_t)(bm + row) * 256 + c8] = vv;
    }
  }
}

// ---------------------------------------------------------------------------
// bucket summaries from packed qkv (ld 768): q at +0, k at +256
// ---------------------------------------------------------------------------
__global__ __launch_bounds__(64)
void summary_k(const ushort* __restrict__ qkv,
               float* __restrict__ sq, float* __restrict__ sk) {
  int blk = blockIdx.x;
  int bh = blk >> 7, ib = blk & 127;
  int b = bh >> 3, h = bh & 7;
  int lane = threadIdx.x;
  int d = lane & 31;
  bool isK = lane >= 32;
  size_t base = ((size_t)b * T_LEN + (size_t)ib * 64) * 768 + (isK ? 256 : 0) + h * 32 + d;
  float s = 0.f;
#pragma unroll 8
  for (int t = 0; t < 64; t++) s += bf2f(qkv[base + (size_t)t * 768]);
  s *= (1.0f / 64.0f);
  float* dst = isK ? sk : sq;
  dst[((size_t)bh * NBUCK + ib) * 32 + d] = s;
}

// ---------------------------------------------------------------------------
// routing
// ---------------------------------------------------------------------------
__global__ __launch_bounds__(64)
void route_k(const float* __restrict__ sq, const float* __restrict__ sk,
             int* __restrict__ ridx, float* __restrict__ rw) {
  int blk = blockIdx.x;
  int bh = blk >> 7, ib = blk & 127;
  int lane = threadIdx.x;
  const float* qrow = sq + ((size_t)bh * NBUCK + ib) * 32;
  const float* k0 = sk + ((size_t)bh * NBUCK + lane) * 32;
  const float* k1 = k0 + 64 * 32;
  float s0 = 0.f, s1 = 0.f;
#pragma unroll
  for (int d = 0; d < 32; d++) {
    float qd = qrow[d];
    s0 += qd * k0[d];
    s1 += qd * k1[d];
  }
  const float sc = 0.17677669529663687f * (4.0f / 3.0f);
  float L0 = s0 * sc, L1 = s1 * sc;
  float m = fmaxf(L0, L1);
#pragma unroll
  for (int off = 32; off; off >>= 1) m = fmaxf(m, __shfl_xor(m, off));
  float Z = expf(L0 - m) + expf(L1 - m);
#pragma unroll
  for (int off = 32; off; off >>= 1) Z += __shfl_xor(Z, off);
  float mv = (L1 > L0) ? L1 : L0;
  int mj = (L1 > L0) ? lane + 64 : lane;
#pragma unroll
  for (int off = 32; off; off >>= 1) {
    float ov = __shfl_xor(mv, off);
    int oj = __shfl_xor(mj, off);
    if (ov > mv || (ov == mv && oj < mj)) { mv = ov; mj = oj; }
  }
  if (lane == 0) {
    ridx[blk] = mj;
    rw[blk] = 1.0f / Z;
  }
}

// ---------------------------------------------------------------------------
// MFMA bucketed attention reading packed qkv (ld 768). Output bf16.
// ---------------------------------------------------------------------------
__global__ __launch_bounds__(256)
void attn_mfma_k(const ushort* __restrict__ qkv,
                 const int* __restrict__ ridx, const float* __restrict__ rw,
                 ushort* __restrict__ o) {
  __shared__ ushort Qs[64][40];
  __shared__ ushort Ks[128][40];
  __shared__ ushort Vt[32][136];
  __shared__ ushort Ps[4][16][136];
  int blk = blockIdx.x;
  int bh = blk >> 7, ib = blk & 127;
  int b = bh >> 3, h = bh & 7;
  int tid = threadIdx.x;
  int jr = ridx[blk];
  float w = rw[blk];
  {
    int r = tid >> 2, c = (tid & 3) << 3;
    const ushort* src = qkv + ((size_t)b * T_LEN + (size_t)ib * 64 + r) * 768 + h * 32 + c;
    *(bf16x8*)&Qs[r][c] = *(const bf16x8*)src;
  }
#pragma unroll
  for (int p = 0; p < 2; p++) {
    int idx = tid + (p << 8);
    int r = idx >> 2, c = (idx & 3) << 3;
    int srcb = (r < 64) ? jr : ib;
    int tt = r & 63;
    const ushort* src = qkv + ((size_t)b * T_LEN + (size_t)srcb * 64 + tt) * 768 + 256 + h * 32 + c;
    *(bf16x8*)&Ks[r][c] = *(const bf16x8*)src;
  }
  {
    int tok = tid >> 1, d0 = (tid & 1) << 4;
    int srcb = (tok < 64) ? jr : ib;
    int tt = tok & 63;
    const ushort* src = qkv + ((size_t)b * T_LEN + (size_t)srcb * 64 + tt) * 768 + 512 + h * 32 + d0;
    bf16x8 v0 = *(const bf16x8*)src;
    bf16x8 v1 = *(const bf16x8*)(src + 8);
#pragma unroll
    for (int j = 0; j < 8; j++) {
      Vt[d0 + j][tok] = (ushort)v0[j];
      Vt[d0 + 8 + j][tok] = (ushort)v1[j];
    }
  }
  __syncthreads();
  int wid = tid >> 6, lane = tid & 63, l15 = lane & 15, quad = lane >> 4;
  bf16x8 aQ = *(const bf16x8*)&Qs[(wid << 4) + l15][quad << 3];
  f32x4 sf[8];
#pragma unroll
  for (int jn = 0; jn < 8; jn++) {
    bf16x8 bK = *(const bf16x8*)&Ks[(jn << 4) + l15][quad << 3];
    f32x4 z = {0.f, 0.f, 0.f, 0.f};
    sf[jn] = __builtin_amdgcn_mfma_f32_16x16x32_bf16(aQ, bK, z, 0, 0, 0);
  }
  const float sc = 0.17677669529663687f;
#pragma unroll
  for (int jn = 0; jn < 8; jn++) {
    float mult = (jn < 4) ? w * sc : sc;
#pragma unroll
    for (int r = 0; r < 4; r++) sf[jn][r] *= mult;
  }
  float mx[4], sm[4], inv[4];
#pragma unroll
  for (int r = 0; r < 4; r++) {
    float m = sf[0][r];
#pragma unroll
    for (int jn = 1; jn < 8; jn++) m = fmaxf(m, sf[jn][r]);
    mx[r] = m;
  }
#pragma unroll
  for (int off = 1; off < 16; off <<= 1)
#pragma unroll
    for (int r = 0; r < 4; r++) mx[r] = fmaxf(mx[r], __shfl_xor(mx[r], off));
#pragma unroll
  for (int r = 0; r < 4; r++) sm[r] = 0.f;
#pragma unroll
  for (int jn = 0; jn < 8; jn++)
#pragma unroll
    for (int r = 0; r < 4; r++) {
      sf[jn][r] = __expf(sf[jn][r] - mx[r]);
      sm[r] += sf[jn][r];
    }
#pragma unroll
  for (int off = 1; off < 16; off <<= 1)
#pragma unroll
    for (int r = 0; r < 4; r++) sm[r] += __shfl_xor(sm[r], off);
#pragma unroll
  for (int r = 0; r < 4; r++) inv[r] = __builtin_amdgcn_rcpf(sm[r]);
#pragma unroll
  for (int jn = 0; jn < 8; jn++) {
    float ws2 = (jn < 4) ? w : 1.f;
#pragma unroll
    for (int r = 0; r < 4; r++)
      Ps[wid][(quad << 2) + r][(jn << 4) + l15] = f2bf(sf[jn][r] * inv[r] * ws2);
  }
  f32x4 of[2];
#pragma unroll
  for (int nd = 0; nd < 2; nd++) { f32x4 z = {0.f, 0.f, 0.f, 0.f}; of[nd] = z; }
#pragma unroll
  for (int kk = 0; kk < 4; kk++) {
    bf16x8 aP = *(const bf16x8*)&Ps[wid][l15][(kk << 5) + (quad << 3)];
#pragma unroll
    for (int nd = 0; nd < 2; nd++) {
      bf16x8 bV = *(const bf16x8*)&Vt[(nd << 4) + l15][(kk << 5) + (quad << 3)];
      of[nd] = __builtin_amdgcn_mfma_f32_16x16x32_bf16(aP, bV, of[nd], 0, 0, 0);
    }
  }
  ushort* obase = o + ((size_t)b * T_LEN + (size_t)ib * 64 + (wid << 4) + (quad << 2)) * 256 + h * 32 + l15;
#pragma unroll
  for (int nd = 0; nd < 2; nd++)
#pragma unroll
    for (int r = 0; r < 4; r++)
      obase[(size_t)r * 256 + (nd << 4)] = f2bf(of[nd][r]);
}

// ---------------------------------------------------------------------------
// out[b,d,t] = yln[b,t,d]
// ---------------------------------------------------------------------------
__global__ __launch_bounds__(256)
void transpose_out_k(const float* __restrict__ yln, float* __restrict__ out) {
  __shared__ float tile[32][33];
  int b  = blockIdx.z;
  int t0 = blockIdx.x * 32;
  int d0 = blockIdx.y * 32;
  int tx = threadIdx.x;
  int ty = threadIdx.y;
#pragma unroll
  for (int k = 0; k < 4; k++) {
    int t = t0 + ty + k * 8;
    tile[ty + k * 8][tx] = yln[((size_t)b * T_LEN + t) * DIMC + d0 + tx];
  }
  __syncthreads();
#pragma unroll
  for (int k = 0; k < 4; k++) {
    int d = d0 + ty + k * 8;
    out[((size_t)b * DIMC + d) * T_LEN + t0 + tx] = tile[tx][ty + k * 8];
  }
}

// ---------------------------------------------------------------------------
extern "C" void kernel_launch(void* const* d_in, const int* in_sizes, int n_in,
                              void* d_out, int out_size, void* d_ws, size_t ws_size,
                              hipStream_t stream) {
  const float* x     = (const float*)d_in[0];
  const float* pe0   = (const float*)d_in[1];
  const float* pe1   = (const float*)d_in[2];
  const float* ln1_g = (const float*)d_in[3];
  const float* ln1_b = (const float*)d_in[4];
  const float* Wq    = (const float*)d_in[5];
  const float* Wkv   = (const float*)d_in[6];
  const float* Wo    = (const float*)d_in[7];
  const float* bo    = (const float*)d_in[8];
  const float* ln2_g = (const float*)d_in[9];
  const float* ln2_b = (const float*)d_in[10];
  const float* W1    = (const float*)d_in[11];
  const float* b1    = (const float*)d_in[12];
  const float* W2    = (const float*)d_in[13];
  const float* b2    = (const float*)d_in[14];
  const float* gf    = (const float*)d_in[15];
  const float* bfp   = (const float*)d_in[16];
  float* out = (float*)d_out;

  const int M = MROWS;
  float*  y    = (float*)d_ws;                       // M*256 f32
  ushort* qkv  = (ushort*)(y + (size_t)M * 256);     // M*768 bf16
  ushort* bufA = qkv + (size_t)M * 768;              // attn out (bf16)
  ushort* bufB = bufA + (size_t)M * 256;             // LN out (bf16)
  ushort* wbf  = bufB + (size_t)M * 256;             // 6*786432 transposed weights
  float*  sqb  = (float*)(wbf + (size_t)6 * 786432);
  float*  skb  = sqb + 131072;
  float*  rwb  = skb + 131072;
  int*    rib  = (int*)(rwb + 4096);
  ushort* ffbf = qkv;   // FF intermediate (M*1024) overlays dead qkv+bufA

  dim3 tb(32, 8);
  wt_bf16_k<<<dim3(8, 8, 6),  tb, 0, stream>>>(Wq,  wbf + 0,      256, 256,  786432);
  wt_bf16_k<<<dim3(16, 8, 6), tb, 0, stream>>>(Wkv, wbf + 65536,  256, 512,  786432);
  wt_bf16_k<<<dim3(8, 8, 6),  tb, 0, stream>>>(Wo,  wbf + 196608, 256, 256,  786432);
  wt_bf16_k<<<dim3(32, 8, 6), tb, 0, stream>>>(W1,  wbf + 262144, 256, 1024, 786432);
  wt_bf16_k<<<dim3(8, 32, 6), tb, 0, stream>>>(W2,  wbf + 524288, 1024, 256, 786432);

  add_pos_k<<<dim3(T_LEN / 32, DIMC / 32, 4), tb, 0, stream>>>(x, pe0, pe1, y);
  layernorm_k<<<M / 4, 256, 0, stream>>>(y, ln1_g, ln1_b, bufB);   // layer-0 LN1

  for (int l = 0; l < 6; l++) {
    const ushort* wl    = wbf + (size_t)l * 786432;
    const ushort* wqkvT = wl;
    const ushort* woT   = wl + 196608;
    const ushort* w1T   = wl + 262144;
    const ushort* w2T   = wl + 524288;

    gemm_bf16<0><<<dim3(M / 128, 6), 256, 0, stream>>>(bufB, wqkvT, nullptr, qkv, 768, 256, 256, 256);
    summary_k<<<BHEAD * NBUCK, 64, 0, stream>>>(qkv, sqb, skb);
    route_k<<<BHEAD * NBUCK, 64, 0, stream>>>(sqb, skb, rib, rwb);
    attn_mfma_k<<<BHEAD * NBUCK, 256, 0, stream>>>(qkv, rib, rwb, bufA);
    // o-proj + bias + residual + LN2 -> bufB (K=256)
    oproj_ln_k<0><<<M / 64, 256, 0, stream>>>(bufA, woT, bo + l * 256, y,
                                              ln2_g + l * 256, ln2_b + l * 256,
                                              bufB, 256, 256);
    // FF1 + gelu -> ffbf (overlays dead qkv+bufA)
    gemm_bf16<1><<<dim3(M / 128, 8), 256, 0, stream>>>(bufB, w1T, b1 + l * 1024, ffbf, 1024, 256, 256, 256);
    // FF2 + bias + residual + LN (next LN1 / final LN), K=1024
    if (l < 5) {
      oproj_ln_k<0><<<M / 64, 256, 0, stream>>>(ffbf, w2T, b2 + l * 256, y,
                                                ln1_g + (l + 1) * 256, ln1_b + (l + 1) * 256,
                                                bufB, 1024, 1024);
    } else {
      oproj_ln_k<1><<<M / 64, 256, 0, stream>>>(ffbf, w2T, b2 + l * 256, y,
                                                gf, bfp, nullptr, 1024, 1024);
    }
  }

  transpose_out_k<<<dim3(T_LEN / 32, DIMC / 32, 4), tb, 0, stream>>>(y, out);

  (void)in_sizes; (void)n_in; (void)out_size; (void)ws_size;
}